// Round 9
// baseline (1097.691 us; speedup 1.0000x reference)
//
#include <hip/hip_runtime.h>

#define BN_EPS 1e-5f

typedef unsigned int uint_t;
typedef unsigned short ushort_t;
typedef short bf16x8 __attribute__((ext_vector_type(8)));
typedef float f32x4 __attribute__((ext_vector_type(4)));

__device__ __forceinline__ float bflo(uint_t v) { return __uint_as_float(v << 16); }
__device__ __forceinline__ float bfhi(uint_t v) { return __uint_as_float(v & 0xffff0000u); }
__device__ __forceinline__ uint_t f2bf(float f) {
    uint_t u = __float_as_uint(f);
    u += 0x7fffu + ((u >> 16) & 1u);
    return u >> 16;
}

__device__ __forceinline__ void acc8(float* a, uint4 g, float w) {
    a[0] = fmaf(bflo(g.x), w, a[0]);
    a[1] = fmaf(bfhi(g.x), w, a[1]);
    a[2] = fmaf(bflo(g.y), w, a[2]);
    a[3] = fmaf(bfhi(g.y), w, a[3]);
    a[4] = fmaf(bflo(g.z), w, a[4]);
    a[5] = fmaf(bfhi(g.z), w, a[5]);
    a[6] = fmaf(bflo(g.w), w, a[6]);
    a[7] = fmaf(bfhi(g.w), w, a[7]);
}

// ---------------- CSR build (self-loop as explicit edge, rows padded to %4) ----------------

__global__ void count_kernel(const int* __restrict__ ei, int* __restrict__ counts, int E) {
    int e = blockIdx.x * blockDim.x + threadIdx.x;
    if (e < E) atomicAdd(&counts[ei[E + e]], 1);
}

// phase 1: per-block (2048 elems) local exclusive scan of padded counts; also isd
__global__ __launch_bounds__(256) void scan_part(const int* __restrict__ counts,
                                                 int* __restrict__ rowptr, int* __restrict__ bsum,
                                                 float* __restrict__ isd, int n) {
    const int tid = threadIdx.x;
    const int lane = tid & 63, wave = tid >> 6;
    __shared__ int wsum[4];
    int idx0 = blockIdx.x * 2048 + tid * 8;
    int v[8];
    int tsum = 0;
#pragma unroll
    for (int j = 0; j < 8; j++) {
        int i = idx0 + j;
        int c = (i < n) ? counts[i] : 0;
        if (i < n) isd[i] = rsqrtf((float)c + 1.0f);
        v[j] = (i < n) ? (((c + 4) >> 2) << 2) : 0;
        tsum += v[j];
    }
    int incl = tsum;
#pragma unroll
    for (int off = 1; off < 64; off <<= 1) {
        int t = __shfl_up(incl, off, 64);
        if (lane >= off) incl += t;
    }
    if (lane == 63) wsum[wave] = incl;
    __syncthreads();
    int wexcl = 0;
    for (int w2 = 0; w2 < wave; w2++) wexcl += wsum[w2];
    int run = wexcl + (incl - tsum);
#pragma unroll
    for (int j = 0; j < 8; j++) {
        int i = idx0 + j;
        if (i < n) rowptr[i] = run;
        run += v[j];
    }
    if (tid == 255) bsum[blockIdx.x] = run;
}

// phase 2: single-wave exclusive scan of block sums (nb <= 64)
__global__ void scan_mid(int* __restrict__ bsum, int nb) {
    int lane = threadIdx.x;
    int v = (lane < nb) ? bsum[lane] : 0;
    int incl = v;
#pragma unroll
    for (int off = 1; off < 64; off <<= 1) {
        int t = __shfl_up(incl, off, 64);
        if (lane >= off) incl += t;
    }
    if (lane < nb) bsum[lane] = incl - v;
    if (lane == 63) bsum[nb] = incl;  // grand total
}

// phase 3: add block offsets + self edge + pad-slot fill (end derived from counts; no race)
__global__ void scan_add_self(int* __restrict__ rowptr, const int* __restrict__ bsum,
                              const int* __restrict__ counts, const float* __restrict__ isd,
                              int* __restrict__ srcs, float* __restrict__ coefs, int n, int nb) {
    int i = blockIdx.x * 256 + threadIdx.x;
    if (i < n) {
        int rp = rowptr[i] + bsum[i >> 11];
        rowptr[i] = rp;
        int c = counts[i];
        int pos = rp + c;
        int end = rp + (((c + 4) >> 2) << 2);
        float v = isd[i];
        srcs[pos] = i;
        coefs[pos] = v * v;
        for (int p = pos + 1; p < end; p++) {
            srcs[p] = i;
            coefs[p] = 0.f;
        }
    } else if (i == n) {
        rowptr[n] = bsum[nb];
    }
}

__global__ void scatter_kernel(const int* __restrict__ ei, const int* __restrict__ rowptr,
                               int* __restrict__ cursor, const float* __restrict__ isd,
                               int* __restrict__ srcs, float* __restrict__ coefs, int E) {
    int e = blockIdx.x * blockDim.x + threadIdx.x;
    if (e < E) {
        int s = ei[e], d = ei[E + e];
        int p = atomicAdd(&cursor[d], 1);
        int idx = rowptr[d] + p;
        srcs[idx] = s;
        coefs[idx] = isd[s] * isd[d];
    }
}

// ---------------- W transpose to bf16: Wt[l][n][k] = bf16(W[l][k][n]) ----------------

__global__ void wtrans_kernel(const float* __restrict__ W, ushort_t* __restrict__ Wt) {
    int id = blockIdx.x * 256 + threadIdx.x;  // over 6*16384
    int l = id >> 14, rem = id & 16383;
    int k = rem >> 7, n = rem & 127;
    Wt[(l << 14) + (n << 7) + k] = f2bf(W[id]);
}

// ---------------- encoder: h0 = relu(x @ Wenc + benc) + atomic BN stats (slot 0) ----------------

__global__ __launch_bounds__(256) void encoder_kernel(const float* __restrict__ x,
                                                      const float* __restrict__ W,
                                                      const float* __restrict__ b,
                                                      float* __restrict__ h0,
                                                      float* __restrict__ stats, int N) {
    int tid = threadIdx.x;
    int g = blockIdx.x * 256 + tid;
    int total = gridDim.x * 256;
    int c = tid & 127;
    float w0 = W[c], w1 = W[128 + c], w2 = W[256 + c], w3 = W[384 + c], bb = b[c];
    float s = 0.f, q = 0.f;
    int tot = N * 128;
    for (int i = g; i < tot; i += total) {
        int n = i >> 7;
        float4 xv = ((const float4*)x)[n];
        float v = fmaf(xv.x, w0, fmaf(xv.y, w1, fmaf(xv.z, w2, fmaf(xv.w, w3, bb))));
        v = fmaxf(v, 0.f);
        h0[i] = v;
        s += v;
        q += v * v;
    }
    __shared__ float ls[256];
    ls[tid] = s;
    __syncthreads();
    if (tid < 128) atomicAdd(&stats[tid], ls[tid] + ls[tid + 128]);
    __syncthreads();
    ls[tid] = q;
    __syncthreads();
    if (tid < 128) atomicAdd(&stats[128 + tid], ls[tid] + ls[tid + 128]);
}

// ---------------- MFMA bf16 GEMM for conv layers ----------------
// Computes scale/shift from stats in-prologue (no separate finalize kernel).
// MODE 0: A = h*sc + sh;  MODE 1: A = h + relu(aggb*sc + sh)  (aggb bf16, row-major)
// Writes updated h (f32) and hwb = bf16(A @ W), row-major [n][128]

#define SWZ(byte, row) ((byte) ^ (((row) & 7) << 4))

template <int MODE>
__global__ __launch_bounds__(256) void mfma_gemm(const float* __restrict__ h,
                                                 const ushort_t* __restrict__ aggb,
                                                 const float* __restrict__ stats,
                                                 const float* __restrict__ g,
                                                 const float* __restrict__ beta, float invN,
                                                 const ushort_t* __restrict__ Wt,
                                                 float* __restrict__ hout,
                                                 ushort_t* __restrict__ hwb, int N) {
    __shared__ ushort_t As[64 * 128];  // bf16 A-tile, XOR-swizzled rows
    __shared__ float s_sc[128], s_sh[128];
    const int tid = threadIdx.x;
    const int row0 = blockIdx.x * 64;

    if (tid < 128) {
        float S = stats[tid], Q = stats[tid + 128];
        float mu = S * invN;
        float var = fmaxf(Q * invN - mu * mu, 0.f);
        float rs = rsqrtf(var + BN_EPS);
        float sc = g[tid] * rs;
        s_sc[tid] = sc;
        s_sh[tid] = beta[tid] - mu * sc;
    }
    __syncthreads();

    // prologue: fused BN(/ReLU/residual) in f32, write h back, stage bf16 tile
#pragma unroll
    for (int j = 0; j < 4; j++) {
        int idx = (j * 256 + tid) * 8;
        int r = idx >> 7, c = idx & 127;
        int grow = row0 + r;
        float av[8] = {0.f, 0.f, 0.f, 0.f, 0.f, 0.f, 0.f, 0.f};
        if (grow < N) {
            float4 h0 = *(const float4*)&h[(size_t)grow * 128 + c];
            float4 h1 = *(const float4*)&h[(size_t)grow * 128 + c + 4];
            float hv[8] = {h0.x, h0.y, h0.z, h0.w, h1.x, h1.y, h1.z, h1.w};
            if (MODE == 0) {
#pragma unroll
                for (int k = 0; k < 8; k++) av[k] = fmaf(hv[k], s_sc[c + k], s_sh[c + k]);
            } else {
                uint4 ag = *(const uint4*)&aggb[(size_t)grow * 128 + c];
                float ga[8] = {bflo(ag.x), bfhi(ag.x), bflo(ag.y), bfhi(ag.y),
                               bflo(ag.z), bfhi(ag.z), bflo(ag.w), bfhi(ag.w)};
#pragma unroll
                for (int k = 0; k < 8; k++)
                    av[k] = hv[k] + fmaxf(fmaf(ga[k], s_sc[c + k], s_sh[c + k]), 0.f);
            }
            *(float4*)&hout[(size_t)grow * 128 + c] = make_float4(av[0], av[1], av[2], av[3]);
            *(float4*)&hout[(size_t)grow * 128 + c + 4] = make_float4(av[4], av[5], av[6], av[7]);
        }
        uint4 p;
        p.x = f2bf(av[0]) | (f2bf(av[1]) << 16);
        p.y = f2bf(av[2]) | (f2bf(av[3]) << 16);
        p.z = f2bf(av[4]) | (f2bf(av[5]) << 16);
        p.w = f2bf(av[6]) | (f2bf(av[7]) << 16);
        *(uint4*)((char*)As + SWZ(r * 256 + c * 2, r)) = p;
    }
    __syncthreads();

    const int w = tid >> 6, l = tid & 63;
    const int mrow = l & 15, kg = l >> 4;
    const int arow = w * 16 + mrow;
    bf16x8 afr[4];
#pragma unroll
    for (int ks = 0; ks < 4; ks++)
        afr[ks] = *(const bf16x8*)((const char*)As + SWZ(arow * 256 + ks * 64 + kg * 16, arow));

    f32x4 acc[8];
#pragma unroll
    for (int nt = 0; nt < 8; nt++) acc[nt] = (f32x4){0.f, 0.f, 0.f, 0.f};

#pragma unroll
    for (int nt = 0; nt < 8; nt++) {
        const ushort_t* wp = &Wt[(size_t)(nt * 16 + mrow) * 128 + kg * 8];
#pragma unroll
        for (int ks = 0; ks < 4; ks++) {
            bf16x8 bfr = *(const bf16x8*)&wp[ks * 32];
            acc[nt] = __builtin_amdgcn_mfma_f32_16x16x32_bf16(afr[ks], bfr, acc[nt], 0, 0, 0);
        }
    }

    // epilogue: C[row=(l>>4)*4+r][col=l&15] per m89-verified layout
#pragma unroll
    for (int nt = 0; nt < 8; nt++) {
#pragma unroll
        for (int r = 0; r < 4; r++) {
            int grow = row0 + w * 16 + kg * 4 + r;
            if (grow < N) hwb[(size_t)grow * 128 + nt * 16 + mrow] = f2bf(acc[nt][r]);
        }
    }
}

// ---------------- f32 fused GEMM (decoder) ----------------
// MODE 1: A = h + relu(aggb*sc + sh)  (stats in-prologue); MODE 2: A = A0 plain

template <int K, int NOUT, int MODE, bool RELU>
__global__ __launch_bounds__(256) void fused_gemm(const float* __restrict__ A0,
                                                  const ushort_t* __restrict__ aggb,
                                                  const float* __restrict__ stats,
                                                  const float* __restrict__ g,
                                                  const float* __restrict__ beta, float invN,
                                                  const float* __restrict__ B,
                                                  const float* __restrict__ bias,
                                                  float* __restrict__ Cf, int N) {
    constexpr int TN = NOUT / 16;
    constexpr int LDA = K + 1;
    __shared__ float As[64 * LDA];
    __shared__ float Bs[16 * NOUT];
    __shared__ float s_sc[128], s_sh[128];
    const int tid = threadIdx.x;
    const int row0 = blockIdx.x * 64;

    if (MODE == 1) {
        if (tid < 128) {
            float S = stats[tid], Q = stats[tid + 128];
            float mu = S * invN;
            float var = fmaxf(Q * invN - mu * mu, 0.f);
            float rs = rsqrtf(var + BN_EPS);
            float sc = g[tid] * rs;
            s_sc[tid] = sc;
            s_sh[tid] = beta[tid] - mu * sc;
        }
        __syncthreads();
#pragma unroll
        for (int j = 0; j < 4; j++) {
            int idx = (j * 256 + tid) * 8;
            int r = idx >> 7, c = idx & 127;
            int grow = row0 + r;
            float av[8] = {0.f, 0.f, 0.f, 0.f, 0.f, 0.f, 0.f, 0.f};
            if (grow < N) {
                float4 h0 = *(const float4*)&A0[(size_t)grow * 128 + c];
                float4 h1 = *(const float4*)&A0[(size_t)grow * 128 + c + 4];
                float hv[8] = {h0.x, h0.y, h0.z, h0.w, h1.x, h1.y, h1.z, h1.w};
                uint4 ag = *(const uint4*)&aggb[(size_t)grow * 128 + c];
                float ga[8] = {bflo(ag.x), bfhi(ag.x), bflo(ag.y), bfhi(ag.y),
                               bflo(ag.z), bfhi(ag.z), bflo(ag.w), bfhi(ag.w)};
#pragma unroll
                for (int k = 0; k < 8; k++)
                    av[k] = hv[k] + fmaxf(fmaf(ga[k], s_sc[c + k], s_sh[c + k]), 0.f);
            }
#pragma unroll
            for (int k = 0; k < 8; k++) As[r * LDA + c + k] = av[k];
        }
    } else {
        constexpr int NF4 = 64 * K / 4 / 256;
#pragma unroll
        for (int j = 0; j < NF4; j++) {
            int idx = (j * 256 + tid) * 4;
            int r = idx / K;
            int c = idx % K;
            int grow = row0 + r;
            float4 a = make_float4(0.f, 0.f, 0.f, 0.f);
            if (grow < N) a = *(const float4*)&A0[(size_t)grow * K + c];
            As[r * LDA + c + 0] = a.x;
            As[r * LDA + c + 1] = a.y;
            As[r * LDA + c + 2] = a.z;
            As[r * LDA + c + 3] = a.w;
        }
    }
    __syncthreads();

    float acc[4][TN];
#pragma unroll
    for (int i = 0; i < 4; i++)
#pragma unroll
        for (int j = 0; j < TN; j++) acc[i][j] = 0.f;

    const int tx = tid & 15, ty = tid >> 4;
    for (int k0 = 0; k0 < K; k0 += 16) {
        for (int f = tid; f < 16 * NOUT / 4; f += 256) {
            int r = f / (NOUT / 4), c4 = (f % (NOUT / 4)) * 4;
            *(float4*)&Bs[r * NOUT + c4] = *(const float4*)&B[(size_t)(k0 + r) * NOUT + c4];
        }
        __syncthreads();
#pragma unroll
        for (int kk = 0; kk < 16; ++kk) {
            float a[4], bf[TN];
#pragma unroll
            for (int i = 0; i < 4; i++) a[i] = As[(ty * 4 + i) * LDA + k0 + kk];
#pragma unroll
            for (int j = 0; j < TN; j++) bf[j] = Bs[kk * NOUT + tx * TN + j];
#pragma unroll
            for (int i = 0; i < 4; i++)
#pragma unroll
                for (int j = 0; j < TN; j++) acc[i][j] = fmaf(a[i], bf[j], acc[i][j]);
        }
        __syncthreads();
    }

#pragma unroll
    for (int i = 0; i < 4; i++) {
        int grow = row0 + ty * 4 + i;
        if (grow >= N) continue;
#pragma unroll
        for (int j = 0; j < TN; j++) {
            int c = tx * TN + j;
            float v = acc[i][j];
            if (bias) v += bias[c];
            if (RELU) v = fmaxf(v, 0.f);
            Cf[(size_t)grow * NOUT + c] = v;
        }
    }
}

// ---------------- aggregation: dynamic work-stealing, 16 gathers in flight per group ----------------
// Each 16-lane group grabs node-pairs from a global ticket until exhausted.
// aggb[n] = bf16( sum_edges hwb[src]*coef ), self loop explicit; 8 edges per chain per iteration.

__global__ __launch_bounds__(256) void agg_kernel(const ushort_t* __restrict__ hwb,
                                                  const int* __restrict__ rowptr,
                                                  const int* __restrict__ srcs,
                                                  const float* __restrict__ coefs,
                                                  ushort_t* __restrict__ aggb,
                                                  float* __restrict__ stats,
                                                  int* __restrict__ ticket, int npairs, int N) {
    const int tid = threadIdx.x;
    const int wave = tid >> 6, lane = tid & 63;
    const int cbase = (lane & 15) * 8;  // 8 bf16 channels per lane
    float s[8], q[8];
#pragma unroll
    for (int j = 0; j < 8; j++) {
        s[j] = 0.f;
        q[j] = 0.f;
    }

    for (;;) {
        int p;
        if ((lane & 15) == 0) p = atomicAdd(ticket, 1);
        p = __shfl(p, lane & 48, 64);  // broadcast from group leader
        if (p >= npairs) break;
        const int n0 = p * 2;
        const int n1 = n0 + 1;
        const bool hasB = n1 < N;
        int ea = rowptr[n0];
        const int eaE = rowptr[n0 + 1];
        int eb = eaE;
        const int ebE = hasB ? rowptr[n1 + 1] : eaE;
        float aA[8] = {0.f, 0.f, 0.f, 0.f, 0.f, 0.f, 0.f, 0.f};
        float aB[8] = {0.f, 0.f, 0.f, 0.f, 0.f, 0.f, 0.f, 0.f};
        while (ea < eaE || eb < ebE) {
            // two clamped quad-blocks per chain -> 16 independent row gathers
            int ca0 = min(ea, eaE - 4), ca1 = min(ea + 4, eaE - 4);
            int cb0 = min(eb, ebE - 4), cb1 = min(eb + 4, ebE - 4);
            int4 svA0 = *(const int4*)&srcs[ca0];
            int4 svA1 = *(const int4*)&srcs[ca1];
            int4 svB0 = *(const int4*)&srcs[cb0];
            int4 svB1 = *(const int4*)&srcs[cb1];
            float4 wvA0 = *(const float4*)&coefs[ca0];
            float4 wvA1 = *(const float4*)&coefs[ca1];
            float4 wvB0 = *(const float4*)&coefs[cb0];
            float4 wvB1 = *(const float4*)&coefs[cb1];
            if (ea >= eaE) wvA0 = make_float4(0.f, 0.f, 0.f, 0.f);
            if (ea + 4 >= eaE) wvA1 = make_float4(0.f, 0.f, 0.f, 0.f);
            if (eb >= ebE) wvB0 = make_float4(0.f, 0.f, 0.f, 0.f);
            if (eb + 4 >= ebE) wvB1 = make_float4(0.f, 0.f, 0.f, 0.f);
            uint4 gA0 = *(const uint4*)&hwb[(size_t)svA0.x * 128 + cbase];
            uint4 gA1 = *(const uint4*)&hwb[(size_t)svA0.y * 128 + cbase];
            uint4 gA2 = *(const uint4*)&hwb[(size_t)svA0.z * 128 + cbase];
            uint4 gA3 = *(const uint4*)&hwb[(size_t)svA0.w * 128 + cbase];
            uint4 gA4 = *(const uint4*)&hwb[(size_t)svA1.x * 128 + cbase];
            uint4 gA5 = *(const uint4*)&hwb[(size_t)svA1.y * 128 + cbase];
            uint4 gA6 = *(const uint4*)&hwb[(size_t)svA1.z * 128 + cbase];
            uint4 gA7 = *(const uint4*)&hwb[(size_t)svA1.w * 128 + cbase];
            uint4 gB0 = *(const uint4*)&hwb[(size_t)svB0.x * 128 + cbase];
            uint4 gB1 = *(const uint4*)&hwb[(size_t)svB0.y * 128 + cbase];
            uint4 gB2 = *(const uint4*)&hwb[(size_t)svB0.z * 128 + cbase];
            uint4 gB3 = *(const uint4*)&hwb[(size_t)svB0.w * 128 + cbase];
            uint4 gB4 = *(const uint4*)&hwb[(size_t)svB1.x * 128 + cbase];
            uint4 gB5 = *(const uint4*)&hwb[(size_t)svB1.y * 128 + cbase];
            uint4 gB6 = *(const uint4*)&hwb[(size_t)svB1.z * 128 + cbase];
            uint4 gB7 = *(const uint4*)&hwb[(size_t)svB1.w * 128 + cbase];
            acc8(aA, gA0, wvA0.x);
            acc8(aA, gA1, wvA0.y);
            acc8(aA, gA2, wvA0.z);
            acc8(aA, gA3, wvA0.w);
            acc8(aA, gA4, wvA1.x);
            acc8(aA, gA5, wvA1.y);
            acc8(aA, gA6, wvA1.z);
            acc8(aA, gA7, wvA1.w);
            acc8(aB, gB0, wvB0.x);
            acc8(aB, gB1, wvB0.y);
            acc8(aB, gB2, wvB0.z);
            acc8(aB, gB3, wvB0.w);
            acc8(aB, gB4, wvB1.x);
            acc8(aB, gB5, wvB1.y);
            acc8(aB, gB6, wvB1.z);
            acc8(aB, gB7, wvB1.w);
            ea = min(ea + 8, eaE);
            eb = min(eb + 8, ebE);
        }
        uint4 pA;
        pA.x = f2bf(aA[0]) | (f2bf(aA[1]) << 16);
        pA.y = f2bf(aA[2]) | (f2bf(aA[3]) << 16);
        pA.z = f2bf(aA[4]) | (f2bf(aA[5]) << 16);
        pA.w = f2bf(aA[6]) | (f2bf(aA[7]) << 16);
        *(uint4*)&aggb[(size_t)n0 * 128 + cbase] = pA;
#pragma unroll
        for (int j = 0; j < 8; j++) {
            s[j] += aA[j];
            q[j] += aA[j] * aA[j];
        }
        if (hasB) {
            uint4 pB;
            pB.x = f2bf(aB[0]) | (f2bf(aB[1]) << 16);
            pB.y = f2bf(aB[2]) | (f2bf(aB[3]) << 16);
            pB.z = f2bf(aB[4]) | (f2bf(aB[5]) << 16);
            pB.w = f2bf(aB[6]) | (f2bf(aB[7]) << 16);
            *(uint4*)&aggb[(size_t)n1 * 128 + cbase] = pB;
#pragma unroll
            for (int j = 0; j < 8; j++) {
                s[j] += aB[j];
                q[j] += aB[j] * aB[j];
            }
        }
    }

    // fold 4 groups per wave, then block-reduce + atomic into this layer's stats slot
#pragma unroll
    for (int j = 0; j < 8; j++) {
        s[j] += __shfl_xor(s[j], 16, 64);
        s[j] += __shfl_xor(s[j], 32, 64);
        q[j] += __shfl_xor(q[j], 16, 64);
        q[j] += __shfl_xor(q[j], 32, 64);
    }
    __shared__ float ls[4][128];
    if (lane < 16) {
#pragma unroll
        for (int j = 0; j < 8; j++) ls[wave][cbase + j] = s[j];
    }
    __syncthreads();
    if (tid < 128) atomicAdd(&stats[tid], ls[0][tid] + ls[1][tid] + ls[2][tid] + ls[3][tid]);
    __syncthreads();
    if (lane < 16) {
#pragma unroll
        for (int j = 0; j < 8; j++) ls[wave][cbase + j] = q[j];
    }
    __syncthreads();
    if (tid < 128) atomicAdd(&stats[128 + tid], ls[0][tid] + ls[1][tid] + ls[2][tid] + ls[3][tid]);
}

// ---------------- decoder final: out = d2 @ W3 + b3 ----------------

__global__ void dec3_kernel(const float* __restrict__ d2, const float* __restrict__ W3,
                            const float* __restrict__ b3, float* __restrict__ out, int N) {
    __shared__ float tile[64 * 33];
    __shared__ float w3s[32];
    int base = blockIdx.x * 64;
    int tid = threadIdx.x;
    if (tid < 32) w3s[tid] = W3[tid];
    for (int f = tid; f < 2048; f += 256) {
        int r = f >> 5, c = f & 31;
        int n = base + r;
        tile[r * 33 + c] = (n < N) ? d2[(size_t)n * 32 + c] : 0.f;
    }
    __syncthreads();
    if (tid < 64) {
        int n = base + tid;
        if (n < N) {
            float s = b3[0];
#pragma unroll
            for (int k = 0; k < 32; k++) s = fmaf(tile[tid * 33 + k], w3s[k], s);
            out[n] = s;
        }
    }
}

// ---------------- host ----------------

extern "C" void kernel_launch(void* const* d_in, const int* in_sizes, int n_in, void* d_out,
                              int out_size, void* d_ws, size_t ws_size, hipStream_t stream) {
    const float* x = (const float*)d_in[0];
    const int* ei = (const int*)d_in[1];
    const float* enc_w = (const float*)d_in[2];
    const float* enc_b = (const float*)d_in[3];
    const float* enc_bn_g = (const float*)d_in[4];
    const float* enc_bn_b = (const float*)d_in[5];
    const float* conv_w = (const float*)d_in[6];
    // d_in[7] = conv_b: cancels in BatchNorm, unused
    const float* bn_g = (const float*)d_in[8];
    const float* bn_b = (const float*)d_in[9];
    const float* dw1 = (const float*)d_in[10];
    const float* db1 = (const float*)d_in[11];
    const float* dw2 = (const float*)d_in[12];
    const float* db2 = (const float*)d_in[13];
    const float* dw3 = (const float*)d_in[14];
    const float* db3 = (const float*)d_in[15];
    float* out = (float*)d_out;

    const int N = in_sizes[0] / 4;  // 50000
    const int E = in_sizes[1] / 2;  // 600000
    const size_t N128 = (size_t)N * 128;
    const int EPMAX = E + 4 * N;  // padded-CSR upper bound
    const float invN = 1.0f / N;
    const int npairs = (N + 1) / 2;

    // workspace layout (~59 MB)
    float* h = (float*)d_ws;                  // N x 128 f32
    ushort_t* aggb = (ushort_t*)(h + N128);   // N x 128 bf16 (row-major)
    ushort_t* hwb = aggb + N128;              // N x 128 bf16 (row-major)
    ushort_t* wt = hwb + N128;                // 6 x 128 x 128 bf16 (W^T)
    float* stats = (float*)(wt + 6 * 16384);  // 7 x 256 (slot l: sum/sumsq)
    int* tickets = (int*)(stats + 7 * 256);   // 8 ticket counters
    float* isd = (float*)(tickets + 8);       // N
    int* counts = (int*)(isd + N);            // N
    int* rowptr = counts + N;                 // N+1
    int* cursor = rowptr + N + 1;             // N
    int* bsum = cursor + N;                   // 65+1
    int* srcs = bsum + 66;                    // EPMAX
    float* coefs = (float*)(srcs + EPMAX);    // EPMAX
    float* d1 = (float*)hwb;                  // reuse: N x 64 f32
    float* d2 = (float*)aggb;                 // reuse: N x 32 f32

    (void)hipMemsetAsync(stats, 0, (7 * 256) * sizeof(float) + 8 * sizeof(int), stream);
    (void)hipMemsetAsync(counts, 0, (size_t)N * sizeof(int), stream);
    (void)hipMemsetAsync(cursor, 0, (size_t)N * sizeof(int), stream);

    const int eb = (E + 255) / 256;
    const int snb = (N + 2047) / 2048;  // scan blocks (<=64)
    count_kernel<<<eb, 256, 0, stream>>>(ei, counts, E);
    scan_part<<<snb, 256, 0, stream>>>(counts, rowptr, bsum, isd, N);
    scan_mid<<<1, 64, 0, stream>>>(bsum, snb);
    scan_add_self<<<(N + 256) / 256, 256, 0, stream>>>(rowptr, bsum, counts, isd, srcs, coefs, N,
                                                       snb);
    scatter_kernel<<<eb, 256, 0, stream>>>(ei, rowptr, cursor, isd, srcs, coefs, E);
    wtrans_kernel<<<384, 256, 0, stream>>>(conv_w, wt);

    encoder_kernel<<<1024, 256, 0, stream>>>(x, enc_w, enc_b, h, stats, N);

    const int gblocks = (N + 63) / 64;

    // layer 0: A = BN(h0) (write back), hwb = A @ W0; stats slot0 from encoder
    mfma_gemm<0><<<gblocks, 256, 0, stream>>>(h, nullptr, stats, enc_bn_g, enc_bn_b, invN, wt, h,
                                              hwb, N);
    agg_kernel<<<1024, 256, 0, stream>>>(hwb, rowptr, srcs, coefs, aggb, stats + 256, &tickets[0],
                                         npairs, N);

    for (int l = 1; l < 6; l++) {
        mfma_gemm<1><<<gblocks, 256, 0, stream>>>(h, aggb, stats + l * 256, bn_g + (l - 1) * 128,
                                                  bn_b + (l - 1) * 128, invN,
                                                  wt + (size_t)l * 16384, h, hwb, N);
        agg_kernel<<<1024, 256, 0, stream>>>(hwb, rowptr, srcs, coefs, aggb,
                                             stats + (l + 1) * 256, &tickets[l], npairs, N);
    }

    // decoder: layer-5 update fused into dec1's prologue (h not written back)
    fused_gemm<128, 64, 1, true><<<gblocks, 256, 0, stream>>>(
        h, aggb, stats + 6 * 256, bn_g + 5 * 128, bn_b + 5 * 128, invN, dw1, db1, d1, N);
    fused_gemm<64, 32, 2, true><<<gblocks, 256, 0, stream>>>(d1, nullptr, nullptr, nullptr,
                                                             nullptr, 0.f, dw2, db2, d2, N);
    dec3_kernel<<<gblocks, 256, 0, stream>>>(d2, dw3, db3, out, N);
}

// Round 10
// 537.699 us; speedup vs baseline: 2.0415x; 2.0415x over previous
//
#include <hip/hip_runtime.h>

#define BN_EPS 1e-5f

typedef unsigned int uint_t;
typedef unsigned short ushort_t;
typedef short bf16x8 __attribute__((ext_vector_type(8)));
typedef float f32x4 __attribute__((ext_vector_type(4)));

__device__ __forceinline__ float bflo(uint_t v) { return __uint_as_float(v << 16); }
__device__ __forceinline__ float bfhi(uint_t v) { return __uint_as_float(v & 0xffff0000u); }
__device__ __forceinline__ uint_t f2bf(float f) {
    uint_t u = __float_as_uint(f);
    u += 0x7fffu + ((u >> 16) & 1u);
    return u >> 16;
}

__device__ __forceinline__ void acc8(float* a, uint4 g, float w) {
    a[0] = fmaf(bflo(g.x), w, a[0]);
    a[1] = fmaf(bfhi(g.x), w, a[1]);
    a[2] = fmaf(bflo(g.y), w, a[2]);
    a[3] = fmaf(bfhi(g.y), w, a[3]);
    a[4] = fmaf(bflo(g.z), w, a[4]);
    a[5] = fmaf(bfhi(g.z), w, a[5]);
    a[6] = fmaf(bflo(g.w), w, a[6]);
    a[7] = fmaf(bfhi(g.w), w, a[7]);
}

// ---------------- CSR build (self-loop as explicit edge, rows padded to %4) ----------------

__global__ void count_kernel(const int* __restrict__ ei, int* __restrict__ counts, int E) {
    int e = blockIdx.x * blockDim.x + threadIdx.x;
    if (e < E) atomicAdd(&counts[ei[E + e]], 1);
}

// phase 1: per-block (2048 elems) local exclusive scan of padded counts; also isd
__global__ __launch_bounds__(256) void scan_part(const int* __restrict__ counts,
                                                 int* __restrict__ rowptr, int* __restrict__ bsum,
                                                 float* __restrict__ isd, int n) {
    const int tid = threadIdx.x;
    const int lane = tid & 63, wave = tid >> 6;
    __shared__ int wsum[4];
    int idx0 = blockIdx.x * 2048 + tid * 8;
    int v[8];
    int tsum = 0;
#pragma unroll
    for (int j = 0; j < 8; j++) {
        int i = idx0 + j;
        int c = (i < n) ? counts[i] : 0;
        if (i < n) isd[i] = rsqrtf((float)c + 1.0f);
        v[j] = (i < n) ? (((c + 4) >> 2) << 2) : 0;
        tsum += v[j];
    }
    int incl = tsum;
#pragma unroll
    for (int off = 1; off < 64; off <<= 1) {
        int t = __shfl_up(incl, off, 64);
        if (lane >= off) incl += t;
    }
    if (lane == 63) wsum[wave] = incl;
    __syncthreads();
    int wexcl = 0;
    for (int w2 = 0; w2 < wave; w2++) wexcl += wsum[w2];
    int run = wexcl + (incl - tsum);
#pragma unroll
    for (int j = 0; j < 8; j++) {
        int i = idx0 + j;
        if (i < n) rowptr[i] = run;
        run += v[j];
    }
    if (tid == 255) bsum[blockIdx.x] = run;
}

// phase 2: single-wave exclusive scan of block sums (nb <= 64)
__global__ void scan_mid(int* __restrict__ bsum, int nb) {
    int lane = threadIdx.x;
    int v = (lane < nb) ? bsum[lane] : 0;
    int incl = v;
#pragma unroll
    for (int off = 1; off < 64; off <<= 1) {
        int t = __shfl_up(incl, off, 64);
        if (lane >= off) incl += t;
    }
    if (lane < nb) bsum[lane] = incl - v;
    if (lane == 63) bsum[nb] = incl;  // grand total
}

// phase 3: add block offsets + self edge + pad-slot fill (end derived from counts; no race)
__global__ void scan_add_self(int* __restrict__ rowptr, const int* __restrict__ bsum,
                              const int* __restrict__ counts, const float* __restrict__ isd,
                              int* __restrict__ srcs, float* __restrict__ coefs, int n, int nb) {
    int i = blockIdx.x * 256 + threadIdx.x;
    if (i < n) {
        int rp = rowptr[i] + bsum[i >> 11];
        rowptr[i] = rp;
        int c = counts[i];
        int pos = rp + c;
        int end = rp + (((c + 4) >> 2) << 2);
        float v = isd[i];
        srcs[pos] = i;
        coefs[pos] = v * v;
        for (int p = pos + 1; p < end; p++) {
            srcs[p] = i;
            coefs[p] = 0.f;
        }
    } else if (i == n) {
        rowptr[n] = bsum[nb];
    }
}

__global__ void scatter_kernel(const int* __restrict__ ei, const int* __restrict__ rowptr,
                               int* __restrict__ cursor, const float* __restrict__ isd,
                               int* __restrict__ srcs, float* __restrict__ coefs, int E) {
    int e = blockIdx.x * blockDim.x + threadIdx.x;
    if (e < E) {
        int s = ei[e], d = ei[E + e];
        int p = atomicAdd(&cursor[d], 1);
        int idx = rowptr[d] + p;
        srcs[idx] = s;
        coefs[idx] = isd[s] * isd[d];
    }
}

// ---------------- W transpose to bf16: Wt[l][n][k] = bf16(W[l][k][n]) ----------------

__global__ void wtrans_kernel(const float* __restrict__ W, ushort_t* __restrict__ Wt) {
    int id = blockIdx.x * 256 + threadIdx.x;  // over 6*16384
    int l = id >> 14, rem = id & 16383;
    int k = rem >> 7, n = rem & 127;
    Wt[(l << 14) + (n << 7) + k] = f2bf(W[id]);
}

// ---------------- encoder: h0 = relu(x @ Wenc + benc) + atomic BN stats (slot 0) ----------------

__global__ __launch_bounds__(256) void encoder_kernel(const float* __restrict__ x,
                                                      const float* __restrict__ W,
                                                      const float* __restrict__ b,
                                                      float* __restrict__ h0,
                                                      float* __restrict__ stats, int N) {
    int tid = threadIdx.x;
    int g = blockIdx.x * 256 + tid;
    int total = gridDim.x * 256;
    int c = tid & 127;
    float w0 = W[c], w1 = W[128 + c], w2 = W[256 + c], w3 = W[384 + c], bb = b[c];
    float s = 0.f, q = 0.f;
    int tot = N * 128;
    for (int i = g; i < tot; i += total) {
        int n = i >> 7;
        float4 xv = ((const float4*)x)[n];
        float v = fmaf(xv.x, w0, fmaf(xv.y, w1, fmaf(xv.z, w2, fmaf(xv.w, w3, bb))));
        v = fmaxf(v, 0.f);
        h0[i] = v;
        s += v;
        q += v * v;
    }
    __shared__ float ls[256];
    ls[tid] = s;
    __syncthreads();
    if (tid < 128) atomicAdd(&stats[tid], ls[tid] + ls[tid + 128]);
    __syncthreads();
    ls[tid] = q;
    __syncthreads();
    if (tid < 128) atomicAdd(&stats[128 + tid], ls[tid] + ls[tid + 128]);
}

// ---------------- MFMA bf16 GEMM for conv layers ----------------
// Computes scale/shift from stats in-prologue (no separate finalize kernel).
// MODE 0: A = h*sc + sh;  MODE 1: A = h + relu(aggb*sc + sh)  (aggb bf16, row-major)
// Writes updated h (f32) and hwb = bf16(A @ W), row-major [n][128]

#define SWZ(byte, row) ((byte) ^ (((row) & 7) << 4))

template <int MODE>
__global__ __launch_bounds__(256) void mfma_gemm(const float* __restrict__ h,
                                                 const ushort_t* __restrict__ aggb,
                                                 const float* __restrict__ stats,
                                                 const float* __restrict__ g,
                                                 const float* __restrict__ beta, float invN,
                                                 const ushort_t* __restrict__ Wt,
                                                 float* __restrict__ hout,
                                                 ushort_t* __restrict__ hwb, int N) {
    __shared__ ushort_t As[64 * 128];  // bf16 A-tile, XOR-swizzled rows
    __shared__ float s_sc[128], s_sh[128];
    const int tid = threadIdx.x;
    const int row0 = blockIdx.x * 64;

    if (tid < 128) {
        float S = stats[tid], Q = stats[tid + 128];
        float mu = S * invN;
        float var = fmaxf(Q * invN - mu * mu, 0.f);
        float rs = rsqrtf(var + BN_EPS);
        float sc = g[tid] * rs;
        s_sc[tid] = sc;
        s_sh[tid] = beta[tid] - mu * sc;
    }
    __syncthreads();

    // prologue: fused BN(/ReLU/residual) in f32, write h back, stage bf16 tile
#pragma unroll
    for (int j = 0; j < 4; j++) {
        int idx = (j * 256 + tid) * 8;
        int r = idx >> 7, c = idx & 127;
        int grow = row0 + r;
        float av[8] = {0.f, 0.f, 0.f, 0.f, 0.f, 0.f, 0.f, 0.f};
        if (grow < N) {
            float4 h0 = *(const float4*)&h[(size_t)grow * 128 + c];
            float4 h1 = *(const float4*)&h[(size_t)grow * 128 + c + 4];
            float hv[8] = {h0.x, h0.y, h0.z, h0.w, h1.x, h1.y, h1.z, h1.w};
            if (MODE == 0) {
#pragma unroll
                for (int k = 0; k < 8; k++) av[k] = fmaf(hv[k], s_sc[c + k], s_sh[c + k]);
            } else {
                uint4 ag = *(const uint4*)&aggb[(size_t)grow * 128 + c];
                float ga[8] = {bflo(ag.x), bfhi(ag.x), bflo(ag.y), bfhi(ag.y),
                               bflo(ag.z), bfhi(ag.z), bflo(ag.w), bfhi(ag.w)};
#pragma unroll
                for (int k = 0; k < 8; k++)
                    av[k] = hv[k] + fmaxf(fmaf(ga[k], s_sc[c + k], s_sh[c + k]), 0.f);
            }
            *(float4*)&hout[(size_t)grow * 128 + c] = make_float4(av[0], av[1], av[2], av[3]);
            *(float4*)&hout[(size_t)grow * 128 + c + 4] = make_float4(av[4], av[5], av[6], av[7]);
        }
        uint4 p;
        p.x = f2bf(av[0]) | (f2bf(av[1]) << 16);
        p.y = f2bf(av[2]) | (f2bf(av[3]) << 16);
        p.z = f2bf(av[4]) | (f2bf(av[5]) << 16);
        p.w = f2bf(av[6]) | (f2bf(av[7]) << 16);
        *(uint4*)((char*)As + SWZ(r * 256 + c * 2, r)) = p;
    }
    __syncthreads();

    const int w = tid >> 6, l = tid & 63;
    const int mrow = l & 15, kg = l >> 4;
    const int arow = w * 16 + mrow;
    bf16x8 afr[4];
#pragma unroll
    for (int ks = 0; ks < 4; ks++)
        afr[ks] = *(const bf16x8*)((const char*)As + SWZ(arow * 256 + ks * 64 + kg * 16, arow));

    f32x4 acc[8];
#pragma unroll
    for (int nt = 0; nt < 8; nt++) acc[nt] = (f32x4){0.f, 0.f, 0.f, 0.f};

#pragma unroll
    for (int nt = 0; nt < 8; nt++) {
        const ushort_t* wp = &Wt[(size_t)(nt * 16 + mrow) * 128 + kg * 8];
#pragma unroll
        for (int ks = 0; ks < 4; ks++) {
            bf16x8 bfr = *(const bf16x8*)&wp[ks * 32];
            acc[nt] = __builtin_amdgcn_mfma_f32_16x16x32_bf16(afr[ks], bfr, acc[nt], 0, 0, 0);
        }
    }

    // epilogue: C[row=(l>>4)*4+r][col=l&15] per m89-verified layout
#pragma unroll
    for (int nt = 0; nt < 8; nt++) {
#pragma unroll
        for (int r = 0; r < 4; r++) {
            int grow = row0 + w * 16 + kg * 4 + r;
            if (grow < N) hwb[(size_t)grow * 128 + nt * 16 + mrow] = f2bf(acc[nt][r]);
        }
    }
}

// ---------------- f32 fused GEMM (decoder) ----------------
// MODE 1: A = h + relu(aggb*sc + sh)  (stats in-prologue); MODE 2: A = A0 plain

template <int K, int NOUT, int MODE, bool RELU>
__global__ __launch_bounds__(256) void fused_gemm(const float* __restrict__ A0,
                                                  const ushort_t* __restrict__ aggb,
                                                  const float* __restrict__ stats,
                                                  const float* __restrict__ g,
                                                  const float* __restrict__ beta, float invN,
                                                  const float* __restrict__ B,
                                                  const float* __restrict__ bias,
                                                  float* __restrict__ Cf, int N) {
    constexpr int TN = NOUT / 16;
    constexpr int LDA = K + 1;
    __shared__ float As[64 * LDA];
    __shared__ float Bs[16 * NOUT];
    __shared__ float s_sc[128], s_sh[128];
    const int tid = threadIdx.x;
    const int row0 = blockIdx.x * 64;

    if (MODE == 1) {
        if (tid < 128) {
            float S = stats[tid], Q = stats[tid + 128];
            float mu = S * invN;
            float var = fmaxf(Q * invN - mu * mu, 0.f);
            float rs = rsqrtf(var + BN_EPS);
            float sc = g[tid] * rs;
            s_sc[tid] = sc;
            s_sh[tid] = beta[tid] - mu * sc;
        }
        __syncthreads();
#pragma unroll
        for (int j = 0; j < 4; j++) {
            int idx = (j * 256 + tid) * 8;
            int r = idx >> 7, c = idx & 127;
            int grow = row0 + r;
            float av[8] = {0.f, 0.f, 0.f, 0.f, 0.f, 0.f, 0.f, 0.f};
            if (grow < N) {
                float4 h0 = *(const float4*)&A0[(size_t)grow * 128 + c];
                float4 h1 = *(const float4*)&A0[(size_t)grow * 128 + c + 4];
                float hv[8] = {h0.x, h0.y, h0.z, h0.w, h1.x, h1.y, h1.z, h1.w};
                uint4 ag = *(const uint4*)&aggb[(size_t)grow * 128 + c];
                float ga[8] = {bflo(ag.x), bfhi(ag.x), bflo(ag.y), bfhi(ag.y),
                               bflo(ag.z), bfhi(ag.z), bflo(ag.w), bfhi(ag.w)};
#pragma unroll
                for (int k = 0; k < 8; k++)
                    av[k] = hv[k] + fmaxf(fmaf(ga[k], s_sc[c + k], s_sh[c + k]), 0.f);
            }
#pragma unroll
            for (int k = 0; k < 8; k++) As[r * LDA + c + k] = av[k];
        }
    } else {
        constexpr int NF4 = 64 * K / 4 / 256;
#pragma unroll
        for (int j = 0; j < NF4; j++) {
            int idx = (j * 256 + tid) * 4;
            int r = idx / K;
            int c = idx % K;
            int grow = row0 + r;
            float4 a = make_float4(0.f, 0.f, 0.f, 0.f);
            if (grow < N) a = *(const float4*)&A0[(size_t)grow * K + c];
            As[r * LDA + c + 0] = a.x;
            As[r * LDA + c + 1] = a.y;
            As[r * LDA + c + 2] = a.z;
            As[r * LDA + c + 3] = a.w;
        }
    }
    __syncthreads();

    float acc[4][TN];
#pragma unroll
    for (int i = 0; i < 4; i++)
#pragma unroll
        for (int j = 0; j < TN; j++) acc[i][j] = 0.f;

    const int tx = tid & 15, ty = tid >> 4;
    for (int k0 = 0; k0 < K; k0 += 16) {
        for (int f = tid; f < 16 * NOUT / 4; f += 256) {
            int r = f / (NOUT / 4), c4 = (f % (NOUT / 4)) * 4;
            *(float4*)&Bs[r * NOUT + c4] = *(const float4*)&B[(size_t)(k0 + r) * NOUT + c4];
        }
        __syncthreads();
#pragma unroll
        for (int kk = 0; kk < 16; ++kk) {
            float a[4], bf[TN];
#pragma unroll
            for (int i = 0; i < 4; i++) a[i] = As[(ty * 4 + i) * LDA + k0 + kk];
#pragma unroll
            for (int j = 0; j < TN; j++) bf[j] = Bs[kk * NOUT + tx * TN + j];
#pragma unroll
            for (int i = 0; i < 4; i++)
#pragma unroll
                for (int j = 0; j < TN; j++) acc[i][j] = fmaf(a[i], bf[j], acc[i][j]);
        }
        __syncthreads();
    }

#pragma unroll
    for (int i = 0; i < 4; i++) {
        int grow = row0 + ty * 4 + i;
        if (grow >= N) continue;
#pragma unroll
        for (int j = 0; j < TN; j++) {
            int c = tx * TN + j;
            float v = acc[i][j];
            if (bias) v += bias[c];
            if (RELU) v = fmaxf(v, 0.f);
            Cf[(size_t)grow * NOUT + c] = v;
        }
    }
}

// ---------------- aggregation: striped static nodes, 4 clamped quads = 16 gathers in flight ----
// 16-lane group handles nodes n = gid, gid+G, ... ; per iteration 16 edges of one node.
// aggb[n] = bf16( sum_edges hwb[src]*coef ), self loop explicit; + BN stats.

__global__ __launch_bounds__(256) void agg_kernel(const ushort_t* __restrict__ hwb,
                                                  const int* __restrict__ rowptr,
                                                  const int* __restrict__ srcs,
                                                  const float* __restrict__ coefs,
                                                  ushort_t* __restrict__ aggb,
                                                  float* __restrict__ stats, int N) {
    const int tid = threadIdx.x;
    const int wave = tid >> 6, lane = tid & 63;
    const int cbase = (lane & 15) * 8;  // 8 bf16 channels per lane
    const int gid = blockIdx.x * 16 + (tid >> 4);
    const int G = gridDim.x * 16;
    float s[8], q[8];
#pragma unroll
    for (int j = 0; j < 8; j++) {
        s[j] = 0.f;
        q[j] = 0.f;
    }

    for (int n = gid; n < N; n += G) {
        const int e0 = rowptr[n], e1 = rowptr[n + 1];
        float a[8] = {0.f, 0.f, 0.f, 0.f, 0.f, 0.f, 0.f, 0.f};
        for (int e = e0; e < e1; e += 16) {
            // 4 clamped quads -> 16 independent row gathers in flight
            int c0 = min(e, e1 - 4);
            int c1 = min(e + 4, e1 - 4);
            int c2 = min(e + 8, e1 - 4);
            int c3 = min(e + 12, e1 - 4);
            int4 sv0 = *(const int4*)&srcs[c0];
            int4 sv1 = *(const int4*)&srcs[c1];
            int4 sv2 = *(const int4*)&srcs[c2];
            int4 sv3 = *(const int4*)&srcs[c3];
            float4 wv0 = *(const float4*)&coefs[c0];
            float4 wv1 = *(const float4*)&coefs[c1];
            float4 wv2 = *(const float4*)&coefs[c2];
            float4 wv3 = *(const float4*)&coefs[c3];
            if (e + 4 >= e1) wv1 = make_float4(0.f, 0.f, 0.f, 0.f);
            if (e + 8 >= e1) wv2 = make_float4(0.f, 0.f, 0.f, 0.f);
            if (e + 12 >= e1) wv3 = make_float4(0.f, 0.f, 0.f, 0.f);
            uint4 g0 = *(const uint4*)&hwb[(size_t)sv0.x * 128 + cbase];
            uint4 g1 = *(const uint4*)&hwb[(size_t)sv0.y * 128 + cbase];
            uint4 g2 = *(const uint4*)&hwb[(size_t)sv0.z * 128 + cbase];
            uint4 g3 = *(const uint4*)&hwb[(size_t)sv0.w * 128 + cbase];
            uint4 g4 = *(const uint4*)&hwb[(size_t)sv1.x * 128 + cbase];
            uint4 g5 = *(const uint4*)&hwb[(size_t)sv1.y * 128 + cbase];
            uint4 g6 = *(const uint4*)&hwb[(size_t)sv1.z * 128 + cbase];
            uint4 g7 = *(const uint4*)&hwb[(size_t)sv1.w * 128 + cbase];
            uint4 g8 = *(const uint4*)&hwb[(size_t)sv2.x * 128 + cbase];
            uint4 g9 = *(const uint4*)&hwb[(size_t)sv2.y * 128 + cbase];
            uint4 g10 = *(const uint4*)&hwb[(size_t)sv2.z * 128 + cbase];
            uint4 g11 = *(const uint4*)&hwb[(size_t)sv2.w * 128 + cbase];
            uint4 g12 = *(const uint4*)&hwb[(size_t)sv3.x * 128 + cbase];
            uint4 g13 = *(const uint4*)&hwb[(size_t)sv3.y * 128 + cbase];
            uint4 g14 = *(const uint4*)&hwb[(size_t)sv3.z * 128 + cbase];
            uint4 g15 = *(const uint4*)&hwb[(size_t)sv3.w * 128 + cbase];
            acc8(a, g0, wv0.x);
            acc8(a, g1, wv0.y);
            acc8(a, g2, wv0.z);
            acc8(a, g3, wv0.w);
            acc8(a, g4, wv1.x);
            acc8(a, g5, wv1.y);
            acc8(a, g6, wv1.z);
            acc8(a, g7, wv1.w);
            acc8(a, g8, wv2.x);
            acc8(a, g9, wv2.y);
            acc8(a, g10, wv2.z);
            acc8(a, g11, wv2.w);
            acc8(a, g12, wv3.x);
            acc8(a, g13, wv3.y);
            acc8(a, g14, wv3.z);
            acc8(a, g15, wv3.w);
        }
        uint4 p;
        p.x = f2bf(a[0]) | (f2bf(a[1]) << 16);
        p.y = f2bf(a[2]) | (f2bf(a[3]) << 16);
        p.z = f2bf(a[4]) | (f2bf(a[5]) << 16);
        p.w = f2bf(a[6]) | (f2bf(a[7]) << 16);
        *(uint4*)&aggb[(size_t)n * 128 + cbase] = p;
#pragma unroll
        for (int j = 0; j < 8; j++) {
            s[j] += a[j];
            q[j] += a[j] * a[j];
        }
    }

    // fold 4 groups per wave, then block-reduce + atomic into this layer's stats slot
#pragma unroll
    for (int j = 0; j < 8; j++) {
        s[j] += __shfl_xor(s[j], 16, 64);
        s[j] += __shfl_xor(s[j], 32, 64);
        q[j] += __shfl_xor(q[j], 16, 64);
        q[j] += __shfl_xor(q[j], 32, 64);
    }
    __shared__ float ls[4][128];
    if (lane < 16) {
#pragma unroll
        for (int j = 0; j < 8; j++) ls[wave][cbase + j] = s[j];
    }
    __syncthreads();
    if (tid < 128) atomicAdd(&stats[tid], ls[0][tid] + ls[1][tid] + ls[2][tid] + ls[3][tid]);
    __syncthreads();
    if (lane < 16) {
#pragma unroll
        for (int j = 0; j < 8; j++) ls[wave][cbase + j] = q[j];
    }
    __syncthreads();
    if (tid < 128) atomicAdd(&stats[128 + tid], ls[0][tid] + ls[1][tid] + ls[2][tid] + ls[3][tid]);
}

// ---------------- decoder final: out = d2 @ W3 + b3 ----------------

__global__ void dec3_kernel(const float* __restrict__ d2, const float* __restrict__ W3,
                            const float* __restrict__ b3, float* __restrict__ out, int N) {
    __shared__ float tile[64 * 33];
    __shared__ float w3s[32];
    int base = blockIdx.x * 64;
    int tid = threadIdx.x;
    if (tid < 32) w3s[tid] = W3[tid];
    for (int f = tid; f < 2048; f += 256) {
        int r = f >> 5, c = f & 31;
        int n = base + r;
        tile[r * 33 + c] = (n < N) ? d2[(size_t)n * 32 + c] : 0.f;
    }
    __syncthreads();
    if (tid < 64) {
        int n = base + tid;
        if (n < N) {
            float s = b3[0];
#pragma unroll
            for (int k = 0; k < 32; k++) s = fmaf(tile[tid * 33 + k], w3s[k], s);
            out[n] = s;
        }
    }
}

// ---------------- host ----------------

extern "C" void kernel_launch(void* const* d_in, const int* in_sizes, int n_in, void* d_out,
                              int out_size, void* d_ws, size_t ws_size, hipStream_t stream) {
    const float* x = (const float*)d_in[0];
    const int* ei = (const int*)d_in[1];
    const float* enc_w = (const float*)d_in[2];
    const float* enc_b = (const float*)d_in[3];
    const float* enc_bn_g = (const float*)d_in[4];
    const float* enc_bn_b = (const float*)d_in[5];
    const float* conv_w = (const float*)d_in[6];
    // d_in[7] = conv_b: cancels in BatchNorm, unused
    const float* bn_g = (const float*)d_in[8];
    const float* bn_b = (const float*)d_in[9];
    const float* dw1 = (const float*)d_in[10];
    const float* db1 = (const float*)d_in[11];
    const float* dw2 = (const float*)d_in[12];
    const float* db2 = (const float*)d_in[13];
    const float* dw3 = (const float*)d_in[14];
    const float* db3 = (const float*)d_in[15];
    float* out = (float*)d_out;

    const int N = in_sizes[0] / 4;  // 50000
    const int E = in_sizes[1] / 2;  // 600000
    const size_t N128 = (size_t)N * 128;
    const int EPMAX = E + 4 * N;  // padded-CSR upper bound
    const float invN = 1.0f / N;

    // workspace layout (~59 MB)
    float* h = (float*)d_ws;                  // N x 128 f32
    ushort_t* aggb = (ushort_t*)(h + N128);   // N x 128 bf16 (row-major)
    ushort_t* hwb = aggb + N128;              // N x 128 bf16 (row-major)
    ushort_t* wt = hwb + N128;                // 6 x 128 x 128 bf16 (W^T)
    float* stats = (float*)(wt + 6 * 16384);  // 7 x 256 (slot l: sum/sumsq)
    float* isd = stats + 7 * 256;             // N
    int* counts = (int*)(isd + N);            // N
    int* rowptr = counts + N;                 // N+1
    int* cursor = rowptr + N + 1;             // N
    int* bsum = cursor + N;                   // 65+1
    int* srcs = bsum + 66;                    // EPMAX
    float* coefs = (float*)(srcs + EPMAX);    // EPMAX
    float* d1 = (float*)hwb;                  // reuse: N x 64 f32
    float* d2 = (float*)aggb;                 // reuse: N x 32 f32

    (void)hipMemsetAsync(stats, 0, 7 * 256 * sizeof(float), stream);
    (void)hipMemsetAsync(counts, 0, (size_t)N * sizeof(int), stream);
    (void)hipMemsetAsync(cursor, 0, (size_t)N * sizeof(int), stream);

    const int eb = (E + 255) / 256;
    const int snb = (N + 2047) / 2048;  // scan blocks (<=64)
    count_kernel<<<eb, 256, 0, stream>>>(ei, counts, E);
    scan_part<<<snb, 256, 0, stream>>>(counts, rowptr, bsum, isd, N);
    scan_mid<<<1, 64, 0, stream>>>(bsum, snb);
    scan_add_self<<<(N + 256) / 256, 256, 0, stream>>>(rowptr, bsum, counts, isd, srcs, coefs, N,
                                                       snb);
    scatter_kernel<<<eb, 256, 0, stream>>>(ei, rowptr, cursor, isd, srcs, coefs, E);
    wtrans_kernel<<<384, 256, 0, stream>>>(conv_w, wt);

    encoder_kernel<<<1024, 256, 0, stream>>>(x, enc_w, enc_b, h, stats, N);

    const int gblocks = (N + 63) / 64;
    const int ablocks = 512;  // 8192 groups, ~6 striped nodes each (degree averaging)

    // layer 0: A = BN(h0) (write back), hwb = A @ W0; stats slot0 from encoder
    mfma_gemm<0><<<gblocks, 256, 0, stream>>>(h, nullptr, stats, enc_bn_g, enc_bn_b, invN, wt, h,
                                              hwb, N);
    agg_kernel<<<ablocks, 256, 0, stream>>>(hwb, rowptr, srcs, coefs, aggb, stats + 256, N);

    for (int l = 1; l < 6; l++) {
        mfma_gemm<1><<<gblocks, 256, 0, stream>>>(h, aggb, stats + l * 256, bn_g + (l - 1) * 128,
                                                  bn_b + (l - 1) * 128, invN,
                                                  wt + (size_t)l * 16384, h, hwb, N);
        agg_kernel<<<ablocks, 256, 0, stream>>>(hwb, rowptr, srcs, coefs, aggb,
                                                stats + (l + 1) * 256, N);
    }

    // decoder: layer-5 update fused into dec1's prologue (h not written back)
    fused_gemm<128, 64, 1, true><<<gblocks, 256, 0, stream>>>(
        h, aggb, stats + 6 * 256, bn_g + 5 * 128, bn_b + 5 * 128, invN, dw1, db1, d1, N);
    fused_gemm<64, 32, 2, true><<<gblocks, 256, 0, stream>>>(d1, nullptr, nullptr, nullptr,
                                                             nullptr, 0.f, dw2, db2, d2, N);
    dec3_kernel<<<gblocks, 256, 0, stream>>>(d2, dw3, db3, out, N);
}

// Round 11
// 525.564 us; speedup vs baseline: 2.0886x; 1.0231x over previous
//
#include <hip/hip_runtime.h>

#define BN_EPS 1e-5f

typedef unsigned int uint_t;
typedef unsigned short ushort_t;
typedef short bf16x8 __attribute__((ext_vector_type(8)));
typedef float f32x4 __attribute__((ext_vector_type(4)));

__device__ __forceinline__ float bflo(uint_t v) { return __uint_as_float(v << 16); }
__device__ __forceinline__ float bfhi(uint_t v) { return __uint_as_float(v & 0xffff0000u); }
__device__ __forceinline__ uint_t f2bf(float f) {
    uint_t u = __float_as_uint(f);
    u += 0x7fffu + ((u >> 16) & 1u);
    return u >> 16;
}

__device__ __forceinline__ void acc8(float* a, uint4 g, float w) {
    a[0] = fmaf(bflo(g.x), w, a[0]);
    a[1] = fmaf(bfhi(g.x), w, a[1]);
    a[2] = fmaf(bflo(g.y), w, a[2]);
    a[3] = fmaf(bfhi(g.y), w, a[3]);
    a[4] = fmaf(bflo(g.z), w, a[4]);
    a[5] = fmaf(bfhi(g.z), w, a[5]);
    a[6] = fmaf(bflo(g.w), w, a[6]);
    a[7] = fmaf(bfhi(g.w), w, a[7]);
}

// ---------------- CSR build (self-loop as explicit edge, rows padded to %4) ----------------
// edge list stored as packed (src:int, coef:f32) pairs -> one 8B random store per edge.

__global__ void count_kernel(const int* __restrict__ ei, int* __restrict__ counts, int E) {
    int e = blockIdx.x * blockDim.x + threadIdx.x;
    if (e < E) atomicAdd(&counts[ei[E + e]], 1);
}

// phase 1: per-block (2048 elems) local exclusive scan of padded counts; also isd
__global__ __launch_bounds__(256) void scan_part(const int* __restrict__ counts,
                                                 int* __restrict__ rowptr, int* __restrict__ bsum,
                                                 float* __restrict__ isd, int n) {
    const int tid = threadIdx.x;
    const int lane = tid & 63, wave = tid >> 6;
    __shared__ int wsum[4];
    int idx0 = blockIdx.x * 2048 + tid * 8;
    int v[8];
    int tsum = 0;
#pragma unroll
    for (int j = 0; j < 8; j++) {
        int i = idx0 + j;
        int c = (i < n) ? counts[i] : 0;
        if (i < n) isd[i] = rsqrtf((float)c + 1.0f);
        v[j] = (i < n) ? (((c + 4) >> 2) << 2) : 0;
        tsum += v[j];
    }
    int incl = tsum;
#pragma unroll
    for (int off = 1; off < 64; off <<= 1) {
        int t = __shfl_up(incl, off, 64);
        if (lane >= off) incl += t;
    }
    if (lane == 63) wsum[wave] = incl;
    __syncthreads();
    int wexcl = 0;
    for (int w2 = 0; w2 < wave; w2++) wexcl += wsum[w2];
    int run = wexcl + (incl - tsum);
#pragma unroll
    for (int j = 0; j < 8; j++) {
        int i = idx0 + j;
        if (i < n) rowptr[i] = run;
        run += v[j];
    }
    if (tid == 255) bsum[blockIdx.x] = run;
}

// phase 2: single-wave exclusive scan of block sums (nb <= 64)
__global__ void scan_mid(int* __restrict__ bsum, int nb) {
    int lane = threadIdx.x;
    int v = (lane < nb) ? bsum[lane] : 0;
    int incl = v;
#pragma unroll
    for (int off = 1; off < 64; off <<= 1) {
        int t = __shfl_up(incl, off, 64);
        if (lane >= off) incl += t;
    }
    if (lane < nb) bsum[lane] = incl - v;
    if (lane == 63) bsum[nb] = incl;  // grand total
}

// phase 3: add block offsets + self edge + pad-slot fill (end derived from counts; no race)
__global__ void scan_add_self(int* __restrict__ rowptr, const int* __restrict__ bsum,
                              const int* __restrict__ counts, const float* __restrict__ isd,
                              int2* __restrict__ edges, int n, int nb) {
    int i = blockIdx.x * 256 + threadIdx.x;
    if (i < n) {
        int rp = rowptr[i] + bsum[i >> 11];
        rowptr[i] = rp;
        int c = counts[i];
        int pos = rp + c;
        int end = rp + (((c + 4) >> 2) << 2);
        float v = isd[i];
        edges[pos] = make_int2(i, __float_as_int(v * v));
        for (int p = pos + 1; p < end; p++) edges[p] = make_int2(i, 0);
    } else if (i == n) {
        rowptr[n] = bsum[nb];
    }
}

__global__ void scatter_kernel(const int* __restrict__ ei, const int* __restrict__ rowptr,
                               int* __restrict__ cursor, const float* __restrict__ isd,
                               int2* __restrict__ edges, int E) {
    int e = blockIdx.x * blockDim.x + threadIdx.x;
    if (e < E) {
        int s = ei[e], d = ei[E + e];
        int p = atomicAdd(&cursor[d], 1);
        edges[rowptr[d] + p] = make_int2(s, __float_as_int(isd[s] * isd[d]));
    }
}

// ---------------- W transpose to bf16: Wt[l][n][k] = bf16(W[l][k][n]) ----------------

__global__ void wtrans_kernel(const float* __restrict__ W, ushort_t* __restrict__ Wt) {
    int id = blockIdx.x * 256 + threadIdx.x;  // over 6*16384
    int l = id >> 14, rem = id & 16383;
    int k = rem >> 7, n = rem & 127;
    Wt[(l << 14) + (n << 7) + k] = f2bf(W[id]);
}

// ---------------- encoder: h0 = relu(x @ Wenc + benc) + atomic BN stats (slot 0) ----------------

__global__ __launch_bounds__(256) void encoder_kernel(const float* __restrict__ x,
                                                      const float* __restrict__ W,
                                                      const float* __restrict__ b,
                                                      float* __restrict__ h0,
                                                      float* __restrict__ stats, int N) {
    int tid = threadIdx.x;
    int g = blockIdx.x * 256 + tid;
    int total = gridDim.x * 256;
    int c = tid & 127;
    float w0 = W[c], w1 = W[128 + c], w2 = W[256 + c], w3 = W[384 + c], bb = b[c];
    float s = 0.f, q = 0.f;
    int tot = N * 128;
    for (int i = g; i < tot; i += total) {
        int n = i >> 7;
        float4 xv = ((const float4*)x)[n];
        float v = fmaf(xv.x, w0, fmaf(xv.y, w1, fmaf(xv.z, w2, fmaf(xv.w, w3, bb))));
        v = fmaxf(v, 0.f);
        h0[i] = v;
        s += v;
        q += v * v;
    }
    __shared__ float ls[256];
    ls[tid] = s;
    __syncthreads();
    if (tid < 128) atomicAdd(&stats[tid], ls[tid] + ls[tid + 128]);
    __syncthreads();
    ls[tid] = q;
    __syncthreads();
    if (tid < 128) atomicAdd(&stats[128 + tid], ls[tid] + ls[tid + 128]);
}

// ---------------- MFMA bf16 GEMM for conv layers (128-row tile, 512 threads) ----------------
// Computes scale/shift from stats in-prologue.
// MODE 0: A = h*sc + sh;  MODE 1: A = h + relu(aggb*sc + sh)  (aggb bf16, row-major)
// Writes updated h (f32) and hwb = bf16(A @ W), row-major [n][128]

#define SWZ(byte, row) ((byte) ^ (((row) & 7) << 4))

template <int MODE>
__global__ __launch_bounds__(512) void mfma_gemm(const float* __restrict__ h,
                                                 const ushort_t* __restrict__ aggb,
                                                 const float* __restrict__ stats,
                                                 const float* __restrict__ g,
                                                 const float* __restrict__ beta, float invN,
                                                 const ushort_t* __restrict__ Wt,
                                                 float* __restrict__ hout,
                                                 ushort_t* __restrict__ hwb, int N) {
    __shared__ ushort_t As[128 * 128];  // bf16 A-tile (32 KB), XOR-swizzled rows
    __shared__ float s_sc[128], s_sh[128];
    const int tid = threadIdx.x;
    const int row0 = blockIdx.x * 128;

    if (tid < 128) {
        float S = stats[tid], Q = stats[tid + 128];
        float mu = S * invN;
        float var = fmaxf(Q * invN - mu * mu, 0.f);
        float rs = rsqrtf(var + BN_EPS);
        float sc = g[tid] * rs;
        s_sc[tid] = sc;
        s_sh[tid] = beta[tid] - mu * sc;
    }
    __syncthreads();

    // prologue: fused BN(/ReLU/residual) in f32, write h back, stage bf16 tile
#pragma unroll
    for (int j = 0; j < 4; j++) {
        int idx = (j * 512 + tid) * 8;
        int r = idx >> 7, c = idx & 127;
        int grow = row0 + r;
        float av[8] = {0.f, 0.f, 0.f, 0.f, 0.f, 0.f, 0.f, 0.f};
        if (grow < N) {
            float4 h0 = *(const float4*)&h[(size_t)grow * 128 + c];
            float4 h1 = *(const float4*)&h[(size_t)grow * 128 + c + 4];
            float hv[8] = {h0.x, h0.y, h0.z, h0.w, h1.x, h1.y, h1.z, h1.w};
            if (MODE == 0) {
#pragma unroll
                for (int k = 0; k < 8; k++) av[k] = fmaf(hv[k], s_sc[c + k], s_sh[c + k]);
            } else {
                uint4 ag = *(const uint4*)&aggb[(size_t)grow * 128 + c];
                float ga[8] = {bflo(ag.x), bfhi(ag.x), bflo(ag.y), bfhi(ag.y),
                               bflo(ag.z), bfhi(ag.z), bflo(ag.w), bfhi(ag.w)};
#pragma unroll
                for (int k = 0; k < 8; k++)
                    av[k] = hv[k] + fmaxf(fmaf(ga[k], s_sc[c + k], s_sh[c + k]), 0.f);
            }
            *(float4*)&hout[(size_t)grow * 128 + c] = make_float4(av[0], av[1], av[2], av[3]);
            *(float4*)&hout[(size_t)grow * 128 + c + 4] = make_float4(av[4], av[5], av[6], av[7]);
        }
        uint4 p;
        p.x = f2bf(av[0]) | (f2bf(av[1]) << 16);
        p.y = f2bf(av[2]) | (f2bf(av[3]) << 16);
        p.z = f2bf(av[4]) | (f2bf(av[5]) << 16);
        p.w = f2bf(av[6]) | (f2bf(av[7]) << 16);
        *(uint4*)((char*)As + SWZ(r * 256 + c * 2, r)) = p;
    }
    __syncthreads();

    const int w = tid >> 6, l = tid & 63;  // 8 waves, wave w owns rows w*16..w*16+15
    const int mrow = l & 15, kg = l >> 4;
    const int arow = w * 16 + mrow;
    bf16x8 afr[4];
#pragma unroll
    for (int ks = 0; ks < 4; ks++)
        afr[ks] = *(const bf16x8*)((const char*)As + SWZ(arow * 256 + ks * 64 + kg * 16, arow));

    f32x4 acc[8];
#pragma unroll
    for (int nt = 0; nt < 8; nt++) acc[nt] = (f32x4){0.f, 0.f, 0.f, 0.f};

#pragma unroll
    for (int nt = 0; nt < 8; nt++) {
        const ushort_t* wp = &Wt[(size_t)(nt * 16 + mrow) * 128 + kg * 8];
#pragma unroll
        for (int ks = 0; ks < 4; ks++) {
            bf16x8 bfr = *(const bf16x8*)&wp[ks * 32];
            acc[nt] = __builtin_amdgcn_mfma_f32_16x16x32_bf16(afr[ks], bfr, acc[nt], 0, 0, 0);
        }
    }

    // epilogue: C[row=(l>>4)*4+r][col=l&15] per m89-verified layout
#pragma unroll
    for (int nt = 0; nt < 8; nt++) {
#pragma unroll
        for (int r = 0; r < 4; r++) {
            int grow = row0 + w * 16 + kg * 4 + r;
            if (grow < N) hwb[(size_t)grow * 128 + nt * 16 + mrow] = f2bf(acc[nt][r]);
        }
    }
}

// ---------------- f32 fused GEMM (decoder) ----------------
// MODE 1: A = h + relu(aggb*sc + sh)  (stats in-prologue); MODE 2: A = A0 plain

template <int K, int NOUT, int MODE, bool RELU>
__global__ __launch_bounds__(256) void fused_gemm(const float* __restrict__ A0,
                                                  const ushort_t* __restrict__ aggb,
                                                  const float* __restrict__ stats,
                                                  const float* __restrict__ g,
                                                  const float* __restrict__ beta, float invN,
                                                  const float* __restrict__ B,
                                                  const float* __restrict__ bias,
                                                  float* __restrict__ Cf, int N) {
    constexpr int TN = NOUT / 16;
    constexpr int LDA = K + 1;
    __shared__ float As[64 * LDA];
    __shared__ float Bs[16 * NOUT];
    __shared__ float s_sc[128], s_sh[128];
    const int tid = threadIdx.x;
    const int row0 = blockIdx.x * 64;

    if (MODE == 1) {
        if (tid < 128) {
            float S = stats[tid], Q = stats[tid + 128];
            float mu = S * invN;
            float var = fmaxf(Q * invN - mu * mu, 0.f);
            float rs = rsqrtf(var + BN_EPS);
            float sc = g[tid] * rs;
            s_sc[tid] = sc;
            s_sh[tid] = beta[tid] - mu * sc;
        }
        __syncthreads();
#pragma unroll
        for (int j = 0; j < 4; j++) {
            int idx = (j * 256 + tid) * 8;
            int r = idx >> 7, c = idx & 127;
            int grow = row0 + r;
            float av[8] = {0.f, 0.f, 0.f, 0.f, 0.f, 0.f, 0.f, 0.f};
            if (grow < N) {
                float4 h0 = *(const float4*)&A0[(size_t)grow * 128 + c];
                float4 h1 = *(const float4*)&A0[(size_t)grow * 128 + c + 4];
                float hv[8] = {h0.x, h0.y, h0.z, h0.w, h1.x, h1.y, h1.z, h1.w};
                uint4 ag = *(const uint4*)&aggb[(size_t)grow * 128 + c];
                float ga[8] = {bflo(ag.x), bfhi(ag.x), bflo(ag.y), bfhi(ag.y),
                               bflo(ag.z), bfhi(ag.z), bflo(ag.w), bfhi(ag.w)};
#pragma unroll
                for (int k = 0; k < 8; k++)
                    av[k] = hv[k] + fmaxf(fmaf(ga[k], s_sc[c + k], s_sh[c + k]), 0.f);
            }
#pragma unroll
            for (int k = 0; k < 8; k++) As[r * LDA + c + k] = av[k];
        }
    } else {
        constexpr int NF4 = 64 * K / 4 / 256;
#pragma unroll
        for (int j = 0; j < NF4; j++) {
            int idx = (j * 256 + tid) * 4;
            int r = idx / K;
            int c = idx % K;
            int grow = row0 + r;
            float4 a = make_float4(0.f, 0.f, 0.f, 0.f);
            if (grow < N) a = *(const float4*)&A0[(size_t)grow * K + c];
            As[r * LDA + c + 0] = a.x;
            As[r * LDA + c + 1] = a.y;
            As[r * LDA + c + 2] = a.z;
            As[r * LDA + c + 3] = a.w;
        }
    }
    __syncthreads();

    float acc[4][TN];
#pragma unroll
    for (int i = 0; i < 4; i++)
#pragma unroll
        for (int j = 0; j < TN; j++) acc[i][j] = 0.f;

    const int tx = tid & 15, ty = tid >> 4;
    for (int k0 = 0; k0 < K; k0 += 16) {
        for (int f = tid; f < 16 * NOUT / 4; f += 256) {
            int r = f / (NOUT / 4), c4 = (f % (NOUT / 4)) * 4;
            *(float4*)&Bs[r * NOUT + c4] = *(const float4*)&B[(size_t)(k0 + r) * NOUT + c4];
        }
        __syncthreads();
#pragma unroll
        for (int kk = 0; kk < 16; ++kk) {
            float a[4], bf[TN];
#pragma unroll
            for (int i = 0; i < 4; i++) a[i] = As[(ty * 4 + i) * LDA + k0 + kk];
#pragma unroll
            for (int j = 0; j < TN; j++) bf[j] = Bs[kk * NOUT + tx * TN + j];
#pragma unroll
            for (int i = 0; i < 4; i++)
#pragma unroll
                for (int j = 0; j < TN; j++) acc[i][j] = fmaf(a[i], bf[j], acc[i][j]);
        }
        __syncthreads();
    }

#pragma unroll
    for (int i = 0; i < 4; i++) {
        int grow = row0 + ty * 4 + i;
        if (grow >= N) continue;
#pragma unroll
        for (int j = 0; j < TN; j++) {
            int c = tx * TN + j;
            float v = acc[i][j];
            if (bias) v += bias[c];
            if (RELU) v = fmaxf(v, 0.f);
            Cf[(size_t)grow * NOUT + c] = v;
        }
    }
}

// ---------------- aggregation: striped static nodes, 4 clamped quads = 16 gathers in flight ----
// 16-lane group handles nodes n = gid, gid+G, ... ; packed (src,coef) edge pairs.
// aggb[n] = bf16( sum_edges hwb[src]*coef ), self loop explicit; + BN stats.

__global__ __launch_bounds__(256) void agg_kernel(const ushort_t* __restrict__ hwb,
                                                  const int* __restrict__ rowptr,
                                                  const int2* __restrict__ edges,
                                                  ushort_t* __restrict__ aggb,
                                                  float* __restrict__ stats, int N) {
    const int tid = threadIdx.x;
    const int wave = tid >> 6, lane = tid & 63;
    const int cbase = (lane & 15) * 8;  // 8 bf16 channels per lane
    const int gid = blockIdx.x * 16 + (tid >> 4);
    const int G = gridDim.x * 16;
    float s[8], q[8];
#pragma unroll
    for (int j = 0; j < 8; j++) {
        s[j] = 0.f;
        q[j] = 0.f;
    }

    for (int n = gid; n < N; n += G) {
        const int e0 = rowptr[n], e1 = rowptr[n + 1];
        float a[8] = {0.f, 0.f, 0.f, 0.f, 0.f, 0.f, 0.f, 0.f};
        for (int e = e0; e < e1; e += 16) {
            // 4 clamped quads -> 16 independent row gathers in flight
            int c0 = min(e, e1 - 4);
            int c1 = min(e + 4, e1 - 4);
            int c2 = min(e + 8, e1 - 4);
            int c3 = min(e + 12, e1 - 4);
            int4 p0a = *(const int4*)&edges[c0];
            int4 p0b = *(const int4*)&edges[c0 + 2];
            int4 p1a = *(const int4*)&edges[c1];
            int4 p1b = *(const int4*)&edges[c1 + 2];
            int4 p2a = *(const int4*)&edges[c2];
            int4 p2b = *(const int4*)&edges[c2 + 2];
            int4 p3a = *(const int4*)&edges[c3];
            int4 p3b = *(const int4*)&edges[c3 + 2];
            float4 wv0 = make_float4(__int_as_float(p0a.y), __int_as_float(p0a.w),
                                     __int_as_float(p0b.y), __int_as_float(p0b.w));
            float4 wv1 = make_float4(__int_as_float(p1a.y), __int_as_float(p1a.w),
                                     __int_as_float(p1b.y), __int_as_float(p1b.w));
            float4 wv2 = make_float4(__int_as_float(p2a.y), __int_as_float(p2a.w),
                                     __int_as_float(p2b.y), __int_as_float(p2b.w));
            float4 wv3 = make_float4(__int_as_float(p3a.y), __int_as_float(p3a.w),
                                     __int_as_float(p3b.y), __int_as_float(p3b.w));
            if (e + 4 >= e1) wv1 = make_float4(0.f, 0.f, 0.f, 0.f);
            if (e + 8 >= e1) wv2 = make_float4(0.f, 0.f, 0.f, 0.f);
            if (e + 12 >= e1) wv3 = make_float4(0.f, 0.f, 0.f, 0.f);
            uint4 g0 = *(const uint4*)&hwb[(size_t)p0a.x * 128 + cbase];
            uint4 g1 = *(const uint4*)&hwb[(size_t)p0a.z * 128 + cbase];
            uint4 g2 = *(const uint4*)&hwb[(size_t)p0b.x * 128 + cbase];
            uint4 g3 = *(const uint4*)&hwb[(size_t)p0b.z * 128 + cbase];
            uint4 g4 = *(const uint4*)&hwb[(size_t)p1a.x * 128 + cbase];
            uint4 g5 = *(const uint4*)&hwb[(size_t)p1a.z * 128 + cbase];
            uint4 g6 = *(const uint4*)&hwb[(size_t)p1b.x * 128 + cbase];
            uint4 g7 = *(const uint4*)&hwb[(size_t)p1b.z * 128 + cbase];
            uint4 g8 = *(const uint4*)&hwb[(size_t)p2a.x * 128 + cbase];
            uint4 g9 = *(const uint4*)&hwb[(size_t)p2a.z * 128 + cbase];
            uint4 g10 = *(const uint4*)&hwb[(size_t)p2b.x * 128 + cbase];
            uint4 g11 = *(const uint4*)&hwb[(size_t)p2b.z * 128 + cbase];
            uint4 g12 = *(const uint4*)&hwb[(size_t)p3a.x * 128 + cbase];
            uint4 g13 = *(const uint4*)&hwb[(size_t)p3a.z * 128 + cbase];
            uint4 g14 = *(const uint4*)&hwb[(size_t)p3b.x * 128 + cbase];
            uint4 g15 = *(const uint4*)&hwb[(size_t)p3b.z * 128 + cbase];
            acc8(a, g0, wv0.x);
            acc8(a, g1, wv0.y);
            acc8(a, g2, wv0.z);
            acc8(a, g3, wv0.w);
            acc8(a, g4, wv1.x);
            acc8(a, g5, wv1.y);
            acc8(a, g6, wv1.z);
            acc8(a, g7, wv1.w);
            acc8(a, g8, wv2.x);
            acc8(a, g9, wv2.y);
            acc8(a, g10, wv2.z);
            acc8(a, g11, wv2.w);
            acc8(a, g12, wv3.x);
            acc8(a, g13, wv3.y);
            acc8(a, g14, wv3.z);
            acc8(a, g15, wv3.w);
        }
        uint4 p;
        p.x = f2bf(a[0]) | (f2bf(a[1]) << 16);
        p.y = f2bf(a[2]) | (f2bf(a[3]) << 16);
        p.z = f2bf(a[4]) | (f2bf(a[5]) << 16);
        p.w = f2bf(a[6]) | (f2bf(a[7]) << 16);
        *(uint4*)&aggb[(size_t)n * 128 + cbase] = p;
#pragma unroll
        for (int j = 0; j < 8; j++) {
            s[j] += a[j];
            q[j] += a[j] * a[j];
        }
    }

    // fold 4 groups per wave, then block-reduce + atomic into this layer's stats slot
#pragma unroll
    for (int j = 0; j < 8; j++) {
        s[j] += __shfl_xor(s[j], 16, 64);
        s[j] += __shfl_xor(s[j], 32, 64);
        q[j] += __shfl_xor(q[j], 16, 64);
        q[j] += __shfl_xor(q[j], 32, 64);
    }
    __shared__ float ls[4][128];
    if (lane < 16) {
#pragma unroll
        for (int j = 0; j < 8; j++) ls[wave][cbase + j] = s[j];
    }
    __syncthreads();
    if (tid < 128) atomicAdd(&stats[tid], ls[0][tid] + ls[1][tid] + ls[2][tid] + ls[3][tid]);
    __syncthreads();
    if (lane < 16) {
#pragma unroll
        for (int j = 0; j < 8; j++) ls[wave][cbase + j] = q[j];
    }
    __syncthreads();
    if (tid < 128) atomicAdd(&stats[128 + tid], ls[0][tid] + ls[1][tid] + ls[2][tid] + ls[3][tid]);
}

// ---------------- decoder final: out = d2 @ W3 + b3 ----------------

__global__ void dec3_kernel(const float* __restrict__ d2, const float* __restrict__ W3,
                            const float* __restrict__ b3, float* __restrict__ out, int N) {
    __shared__ float tile[64 * 33];
    __shared__ float w3s[32];
    int base = blockIdx.x * 64;
    int tid = threadIdx.x;
    if (tid < 32) w3s[tid] = W3[tid];
    for (int f = tid; f < 2048; f += 256) {
        int r = f >> 5, c = f & 31;
        int n = base + r;
        tile[r * 33 + c] = (n < N) ? d2[(size_t)n * 32 + c] : 0.f;
    }
    __syncthreads();
    if (tid < 64) {
        int n = base + tid;
        if (n < N) {
            float s = b3[0];
#pragma unroll
            for (int k = 0; k < 32; k++) s = fmaf(tile[tid * 33 + k], w3s[k], s);
            out[n] = s;
        }
    }
}

// ---------------- host ----------------

extern "C" void kernel_launch(void* const* d_in, const int* in_sizes, int n_in, void* d_out,
                              int out_size, void* d_ws, size_t ws_size, hipStream_t stream) {
    const float* x = (const float*)d_in[0];
    const int* ei = (const int*)d_in[1];
    const float* enc_w = (const float*)d_in[2];
    const float* enc_b = (const float*)d_in[3];
    const float* enc_bn_g = (const float*)d_in[4];
    const float* enc_bn_b = (const float*)d_in[5];
    const float* conv_w = (const float*)d_in[6];
    // d_in[7] = conv_b: cancels in BatchNorm, unused
    const float* bn_g = (const float*)d_in[8];
    const float* bn_b = (const float*)d_in[9];
    const float* dw1 = (const float*)d_in[10];
    const float* db1 = (const float*)d_in[11];
    const float* dw2 = (const float*)d_in[12];
    const float* db2 = (const float*)d_in[13];
    const float* dw3 = (const float*)d_in[14];
    const float* db3 = (const float*)d_in[15];
    float* out = (float*)d_out;

    const int N = in_sizes[0] / 4;  // 50000
    const int E = in_sizes[1] / 2;  // 600000
    const size_t N128 = (size_t)N * 128;
    const int EPMAX = E + 4 * N;  // padded-CSR upper bound
    const float invN = 1.0f / N;

    // workspace layout (~59 MB)
    float* h = (float*)d_ws;                  // N x 128 f32
    ushort_t* aggb = (ushort_t*)(h + N128);   // N x 128 bf16 (row-major)
    ushort_t* hwb = aggb + N128;              // N x 128 bf16 (row-major)
    ushort_t* wt = hwb + N128;                // 6 x 128 x 128 bf16 (W^T)
    float* stats = (float*)(wt + 6 * 16384);  // 7 x 256 (slot l: sum/sumsq)
    float* isd = stats + 7 * 256;             // N
    int* counts = (int*)(isd + N);            // N
    int* rowptr = counts + N;                 // N+1
    int* cursor = rowptr + N + 1;             // N
    int* bsum = cursor + N;                   // 65+1
    int2* edges = (int2*)(bsum + 66);         // EPMAX pairs (src, coef)
    float* d1 = (float*)hwb;                  // reuse: N x 64 f32
    float* d2 = (float*)aggb;                 // reuse: N x 32 f32

    (void)hipMemsetAsync(stats, 0, 7 * 256 * sizeof(float), stream);
    (void)hipMemsetAsync(counts, 0, (size_t)N * sizeof(int), stream);
    (void)hipMemsetAsync(cursor, 0, (size_t)N * sizeof(int), stream);

    const int eb = (E + 255) / 256;
    const int snb = (N + 2047) / 2048;  // scan blocks (<=64)
    count_kernel<<<eb, 256, 0, stream>>>(ei, counts, E);
    scan_part<<<snb, 256, 0, stream>>>(counts, rowptr, bsum, isd, N);
    scan_mid<<<1, 64, 0, stream>>>(bsum, snb);
    scan_add_self<<<(N + 256) / 256, 256, 0, stream>>>(rowptr, bsum, counts, isd, edges, N, snb);
    scatter_kernel<<<eb, 256, 0, stream>>>(ei, rowptr, cursor, isd, edges, E);
    wtrans_kernel<<<384, 256, 0, stream>>>(conv_w, wt);

    encoder_kernel<<<1024, 256, 0, stream>>>(x, enc_w, enc_b, h, stats, N);

    const int mblocks = (N + 127) / 128;
    const int gblocks = (N + 63) / 64;
    const int ablocks = 512;  // 8192 groups, ~6 striped nodes each (degree averaging)

    // layer 0: A = BN(h0) (write back), hwb = A @ W0; stats slot0 from encoder
    mfma_gemm<0><<<mblocks, 512, 0, stream>>>(h, nullptr, stats, enc_bn_g, enc_bn_b, invN, wt, h,
                                              hwb, N);
    agg_kernel<<<ablocks, 256, 0, stream>>>(hwb, rowptr, edges, aggb, stats + 256, N);

    for (int l = 1; l < 6; l++) {
        mfma_gemm<1><<<mblocks, 512, 0, stream>>>(h, aggb, stats + l * 256, bn_g + (l - 1) * 128,
                                                  bn_b + (l - 1) * 128, invN,
                                                  wt + (size_t)l * 16384, h, hwb, N);
        agg_kernel<<<ablocks, 256, 0, stream>>>(hwb, rowptr, edges, aggb, stats + (l + 1) * 256,
                                                N);
    }

    // decoder: layer-5 update fused into dec1's prologue (h not written back)
    fused_gemm<128, 64, 1, true><<<gblocks, 256, 0, stream>>>(
        h, aggb, stats + 6 * 256, bn_g + 5 * 128, bn_b + 5 * 128, invN, dw1, db1, d1, N);
    fused_gemm<64, 32, 2, true><<<gblocks, 256, 0, stream>>>(d1, nullptr, nullptr, nullptr,
                                                             nullptr, 0.f, dw2, db2, d2, N);
    dec3_kernel<<<gblocks, 256, 0, stream>>>(d2, dw3, db3, out, N);
}